// Round 5
// baseline (58.665 us; speedup 1.0000x reference)
//
#include <hip/hip_runtime.h>
#include <cmath>

// GRNN_3547642986522 — B=4096 filters, T=2048 steps.
// Decomposition: cov (Riccati) via closed-form LFT (Euler step == Kalman LFT
// step to O(dt^2)); the per-segment LFT matrix ML is CONSTANT -> host computes
// ML = M_step^LSEG in double; each block gets ML^s by in-register binary
// exponentiation (<=11 mat4 mults, hidden under in-flight dy loads). x is
// affine given cov (per-segment 2x2 transfer X / offset Q); f linear; t closed.
// k1: per (bg,s): O(1) checkpoint, accumulate X/Q over segment, write PQ.
// k2: per (bg,s): O(1) checkpoint + PQ prefix fold -> x at seg start; replay
//     emitting dy_hat (LDS-staged f4 stores). s==S-1 writes nstate & fnew.
// ws: PQ planes [6][S][B] only. S=64 -> 6.29 MiB (fallback 32 / 16).

#define NBATCH 4096
#define NT     2048
#define ROWF4  1024   // float4 per dy row

struct M16 { float m[16]; };   // LFT matrix [[E,F],[G,H]] row-major 4x4

namespace gk {

constexpr float DT   = 0.001f;
constexpr float A00  = -0.15f;
constexpr float A01  = 6.283185f;
constexpr float A10  = -6.283185f;
constexpr float A11  = -0.15f;
constexpr float C0   = 1.6970562748477141f;
constexpr float DD   = 5.25f;

constexpr float P00c = 1.0f + DT*A00;
constexpr float P01c = DT*A01;
constexpr float P10c = DT*A10;
constexpr float P11c = 1.0f + DT*A11;
constexpr float DTC  = DT*C0;
constexpr float QQ   = DT*C0*C0;
constexpr float cVA  = 1.0f + 2.0f*DT*A00;
constexpr float cVB  = 2.0f*DT*A01;
constexpr float cVBn = 2.0f*DT*A10;
constexpr float cVD  = DT*DD;
constexpr float cCA  = 1.0f + DT*(A00+A11);
constexpr float cCB  = DT*A10;
constexpr float cCC  = DT*A01;
constexpr float YC   = C0*DT;

template<int S>
struct cfg {
    static constexpr int LSEG  = NT / S;
    static constexpr int NCHK  = LSEG / 32;
    static constexpr int LDSW  = 36;              // 32 data floats + 4 pad per chunk-row
    static constexpr int SEGF4 = LSEG / 2;
    static constexpr int PLANE = S * NBATCH;
    static constexpr int LOG2L = (LSEG == 32) ? 5 : (LSEG == 64) ? 6 : 7;
};

__device__ __forceinline__ void cov_step(float& vx, float& vp, float& cxp)
{
    float a1 = fmaf(-QQ, vx,  cVA);
    float b1 = fmaf(cVB, cxp, cVD);
    float a2 = fmaf(-QQ, cxp, cVBn);
    float b2 = fmaf(a2,  cxp, cVD);
    float a3 = fmaf(-QQ, vx,  cCA);
    float m  = cCC * vp;
    float c3 = fmaf(cCB, vx,  m);
    float nvx = fmaf(a1,  vx,  b1);
    float nvp = fmaf(cVA, vp,  b2);
    float ncx = fmaf(a3,  cxp, c3);
    vx = nvx; vp = nvp; cxp = ncx;
}

__device__ __forceinline__ void covf_step(
    float& vx, float& vp, float& cxp, float& f0, float& f1,
    float k00, float k01, float k10, float k11,
    float& xi0o, float& xi1o, float& nf0o)
{
    float xi0 = C0*vx, xi1 = C0*cxp;
    float nf0 = fmaf(DT, fmaf(k00, f0, k01*f1), f0);
    float nf1 = fmaf(DT, fmaf(k10, f0, k11*f1), f1);
    xi0o = xi0; xi1o = xi1; nf0o = nf0;
    cov_step(vx, vp, cxp);
    f0 = nf0; f1 = nf1;
}

__device__ __forceinline__ void mat4_mul(const float* A, const float* B, float* C)
{
    #pragma unroll
    for (int i = 0; i < 4; ++i)
        #pragma unroll
        for (int j = 0; j < 4; ++j) {
            float acc = A[i*4+0] * B[0*4+j];
            acc = fmaf(A[i*4+1], B[1*4+j], acc);
            acc = fmaf(A[i*4+2], B[2*4+j], acc);
            acc = fmaf(A[i*4+3], B[3*4+j], acc);
            C[i*4+j] = acc;
        }
}

// P -> (E P + F)(G P + H)^-1 for M=[[E,F],[G,H]], P=[[vx,cxp],[cxp,vp]].
__device__ __forceinline__ void lft_apply(const float* m, float& vx, float& vp, float& cxp)
{
    float n00 = fmaf(m[0], vx,  fmaf(m[1], cxp, m[2]));
    float n01 = fmaf(m[0], cxp, fmaf(m[1], vp,  m[3]));
    float n10 = fmaf(m[4], vx,  fmaf(m[5], cxp, m[6]));
    float n11 = fmaf(m[4], cxp, fmaf(m[5], vp,  m[7]));
    float d00 = fmaf(m[8],  vx,  fmaf(m[9],  cxp, m[10]));
    float d01 = fmaf(m[8],  cxp, fmaf(m[9],  vp,  m[11]));
    float d10 = fmaf(m[12], vx,  fmaf(m[13], cxp, m[14]));
    float d11 = fmaf(m[12], cxp, fmaf(m[13], vp,  m[15]));
    float rdet = 1.0f / fmaf(d00, d11, -d01*d10);
    float p00 = fmaf(n00, d11, -n01*d10) * rdet;
    float p01 = fmaf(n01, d00, -n00*d01) * rdet;
    float p10 = fmaf(n10, d11, -n11*d10) * rdet;
    float p11 = fmaf(n11, d00, -n10*d01) * rdet;
    vx = p00; vp = p11; cxp = 0.5f*(p01 + p10);
}

// O(1)-ish per-block checkpoint: cov via lft(ML^s), f via ((I+dtK)^LSEG)^s.
// Binary exponentiation, register arrays, wave-uniform loops.
template<int S>
__device__ __forceinline__ void seg_checkpoint(
    const M16& ml, int s, const float* state, const float* fin, int b,
    float k00, float k01, float k10, float k11,
    float& vx, float& vp, float& cxp, float& f0, float& f1)
{
    using namespace gk;
    vx = state[b*6+2]; vp = state[b*6+3]; cxp = state[b*6+4];
    f0 = fin[b*2+0];   f1 = fin[b*2+1];

    float acc[16] = {1,0,0,0, 0,1,0,0, 0,0,1,0, 0,0,0,1};
    float bas[16];
    #pragma unroll
    for (int i = 0; i < 16; ++i) bas[i] = ml.m[i];
    int e = s;
    #pragma unroll 1
    while (e) {
        float t[16];
        if (e & 1) {
            mat4_mul(acc, bas, t);
            #pragma unroll
            for (int i = 0; i < 16; ++i) acc[i] = t[i];
        }
        e >>= 1;
        if (e) {
            mat4_mul(bas, bas, t);
            #pragma unroll
            for (int i = 0; i < 16; ++i) bas[i] = t[i];
        }
    }
    lft_apply(acc, vx, vp, cxp);

    // MfL = (I + dt K)^LSEG
    float m00 = fmaf(DT,k00,1.f), m01 = DT*k01;
    float m10 = DT*k10,           m11 = fmaf(DT,k11,1.f);
    #pragma unroll
    for (int i = 0; i < cfg<S>::LOG2L; ++i) {
        float a = fmaf(m00,m00, m01*m10);
        float q = fmaf(m00,m01, m01*m11);
        float c = fmaf(m10,m00, m11*m10);
        float d = fmaf(m10,m01, m11*m11);
        m00=a; m01=q; m10=c; m11=d;
    }
    // MfL^s
    float a00=1.f, a01=0.f, a10=0.f, a11=1.f;
    e = s;
    #pragma unroll 1
    while (e) {
        if (e & 1) {
            float x0 = fmaf(a00,m00, a01*m10);
            float x1 = fmaf(a00,m01, a01*m11);
            float x2 = fmaf(a10,m00, a11*m10);
            float x3 = fmaf(a10,m01, a11*m11);
            a00=x0; a01=x1; a10=x2; a11=x3;
        }
        e >>= 1;
        if (e) {
            float x0 = fmaf(m00,m00, m01*m10);
            float x1 = fmaf(m00,m01, m01*m11);
            float x2 = fmaf(m10,m00, m11*m10);
            float x3 = fmaf(m10,m01, m11*m11);
            m00=x0; m01=x1; m10=x2; m11=x3;
        }
    }
    float nf0 = fmaf(a00, f0, a01*f1);
    float nf1 = fmaf(a10, f0, a11*f1);
    f0 = nf0; f1 = nf1;
}

__device__ __forceinline__ float f4c(const float4& q, int c) {
    return c==0 ? q.x : c==1 ? q.y : c==2 ? q.z : q.w;
}
__device__ __forceinline__ void f4set(float4& q, int c, float v) {
    if (c==0) q.x=v; else if (c==1) q.y=v; else if (c==2) q.z=v; else q.w=v;
}

template<int S>
__device__ __forceinline__ void issue_loads(float4* stg, const float4* dy4,
                                            int b0, int s, int c, int lane)
{
    const int p = lane & 15, rl = lane >> 4;
    const float4* base = dy4 + (size_t)(b0 + rl) * ROWF4
                       + s*cfg<S>::SEGF4 + c*16 + p;
    #pragma unroll
    for (int i = 0; i < 16; ++i)
        stg[i] = base[(size_t)i * 4 * ROWF4];
}

} // namespace gk

// ---------------------------------------------------------------- k1
template<int S>
__global__ void __launch_bounds__(64, 3)
k1_xq(const float* __restrict__ dy, const float* __restrict__ state,
      const float* __restrict__ fin, const float* __restrict__ kp,
      M16 mc, float* __restrict__ ws)
{
    using namespace gk;
    constexpr int NCHK = cfg<S>::NCHK, LDSW = cfg<S>::LDSW, PLANE = cfg<S>::PLANE;
    __shared__ float lds[64][LDSW];
    const int lane = threadIdx.x;
    const int b0   = blockIdx.x * 64, s = blockIdx.y, b = b0 + lane;
    const int p    = lane & 15, rl = lane >> 4;
    const float k00 = kp[0], k01 = kp[1], k10 = kp[2], k11 = kp[3];

    const float4* dy4 = reinterpret_cast<const float4*>(dy);
    float4 stg[16];
    issue_loads<S>(stg, dy4, b0, s, 0, lane);   // in flight during checkpoint

    float vx, vp, cxp, f0, f1;
    seg_checkpoint<S>(mc, s, state, fin, b, k00, k01, k10, k11, vx, vp, cxp, f0, f1);

    float X00 = 1.f, X01 = 0.f, X10 = 0.f, X11 = 1.f, Q0 = 0.f, Q1 = 0.f;

    #pragma unroll 1
    for (int c = 0; c < NCHK; ++c) {
        #pragma unroll
        for (int i = 0; i < 16; ++i) {
            int row = 4*i + rl;
            *reinterpret_cast<float2*>(&lds[row][2*p]) =
                make_float2(stg[i].x, stg[i].z);
        }
        if (c < NCHK-1) issue_loads<S>(stg, dy4, b0, s, c+1, lane);
        asm volatile("s_waitcnt lgkmcnt(0)" ::: "memory");
        __builtin_amdgcn_sched_barrier(0);

        float4 v[8];
        #pragma unroll
        for (int i = 0; i < 8; ++i)
            v[i] = *reinterpret_cast<const float4*>(&lds[lane][4*i]);

        #pragma unroll
        for (int i = 0; i < 32; ++i) {
            float dy0 = f4c(v[i>>2], i & 3);
            float xi0, xi1, nf0;
            covf_step(vx, vp, cxp, f0, f1, k00, k01, k10, k11, xi0, xi1, nf0);
            float p00 = fmaf(-DTC, xi0, P00c);
            float p10 = fmaf(-DTC, xi1, P10c);
            float r0  = xi0*dy0;
            float r1  = fmaf(DT, nf0, xi1*dy0);
            float nX00 = fmaf(p00, X00, P01c*X10);
            float nX01 = fmaf(p00, X01, P01c*X11);
            float nX10 = fmaf(p10, X00, P11c*X10);
            float nX11 = fmaf(p10, X01, P11c*X11);
            float nQ0  = fmaf(p00, Q0, fmaf(P01c, Q1, r0));
            float nQ1  = fmaf(p10, Q0, fmaf(P11c, Q1, r1));
            X00 = nX00; X01 = nX01; X10 = nX10; X11 = nX11; Q0 = nQ0; Q1 = nQ1;
        }
    }

    float* PQ = ws;
    const int sb = s*NBATCH + b;
    PQ[0*PLANE+sb] = X00;  PQ[1*PLANE+sb] = X01;
    PQ[2*PLANE+sb] = X10;  PQ[3*PLANE+sb] = X11;
    PQ[4*PLANE+sb] = Q0;   PQ[5*PLANE+sb] = Q1;
}

// ---------------------------------------------------------------- k2
template<int S>
__global__ void __launch_bounds__(64, 3)
k2_replay(const float* __restrict__ dy, const float* __restrict__ state,
          const float* __restrict__ fin, const float* __restrict__ kp,
          M16 mc, const float* __restrict__ ws, float* __restrict__ out)
{
    using namespace gk;
    constexpr int NCHK = cfg<S>::NCHK, LDSW = cfg<S>::LDSW, PLANE = cfg<S>::PLANE;
    __shared__ float lds[64][LDSW];
    const int lane = threadIdx.x;
    const int b0   = blockIdx.x * 64, s = blockIdx.y, b = b0 + lane;
    const int p    = lane & 15, rl = lane >> 4;
    const float k00 = kp[0], k01 = kp[1], k10 = kp[2], k11 = kp[3];

    const float4* dy4 = reinterpret_cast<const float4*>(dy);
    float4 stg[16];
    issue_loads<S>(stg, dy4, b0, s, 0, lane);   // in flight during fold

    float vx, vp, cxp, f0, f1;
    seg_checkpoint<S>(mc, s, state, fin, b, k00, k01, k10, k11, vx, vp, cxp, f0, f1);

    const float* PQ = ws;
    float x0 = state[b*6+0], x1 = state[b*6+1];
    #pragma unroll 1
    for (int s2 = 0; s2 < s; ++s2) {
        const int q = s2*NBATCH + b;
        float Y00 = PQ[0*PLANE+q], Y01 = PQ[1*PLANE+q];
        float Y10 = PQ[2*PLANE+q], Y11 = PQ[3*PLANE+q];
        float R0  = PQ[4*PLANE+q], R1  = PQ[5*PLANE+q];
        float nx0 = fmaf(Y00, x0, fmaf(Y01, x1, R0));
        float nx1 = fmaf(Y10, x0, fmaf(Y11, x1, R1));
        x0 = nx0; x1 = nx1;
    }

    float4* dh4 = reinterpret_cast<float4*>(out + 6*NBATCH);

    #pragma unroll 1
    for (int c = 0; c < NCHK; ++c) {
        #pragma unroll
        for (int i = 0; i < 16; ++i) {
            int row = 4*i + rl;
            *reinterpret_cast<float2*>(&lds[row][2*p]) =
                make_float2(stg[i].x, stg[i].z);
        }
        if (c < NCHK-1) issue_loads<S>(stg, dy4, b0, s, c+1, lane);
        asm volatile("s_waitcnt lgkmcnt(0)" ::: "memory");
        __builtin_amdgcn_sched_barrier(0);

        float4 v[8];
        #pragma unroll
        for (int i = 0; i < 8; ++i)
            v[i] = *reinterpret_cast<const float4*>(&lds[lane][4*i]);

        #pragma unroll
        for (int i = 0; i < 32; ++i) {
            float dy0 = f4c(v[i>>2], i & 3);
            float yh  = YC * x0;              // pre-update x
            f4set(v[i>>2], i & 3, yh);
            float xi0, xi1, nf0;
            covf_step(vx, vp, cxp, f0, f1, k00, k01, k10, k11, xi0, xi1, nf0);
            float p00 = fmaf(-DTC, xi0, P00c);
            float p10 = fmaf(-DTC, xi1, P10c);
            float r0  = xi0*dy0;
            float r1  = fmaf(DT, nf0, xi1*dy0);
            float nx0 = fmaf(p00, x0, fmaf(P01c, x1, r0));
            float nx1 = fmaf(p10, x0, fmaf(P11c, x1, r1));
            x0 = nx0; x1 = nx1;
        }
        #pragma unroll
        for (int i = 0; i < 8; ++i)
            *reinterpret_cast<float4*>(&lds[lane][4*i]) = v[i];
        asm volatile("s_waitcnt lgkmcnt(0)" ::: "memory");
        __builtin_amdgcn_sched_barrier(0);

        #pragma unroll
        for (int i = 0; i < 16; ++i) {
            int row = 4*i + rl;
            float2 v2 = *reinterpret_cast<const float2*>(&lds[row][2*p]);
            dh4[(size_t)(b0+row)*ROWF4 + s*cfg<S>::SEGF4 + c*16 + p] =
                make_float4(v2.x, 0.f, v2.y, 0.f);
        }
    }

    if (s == S-1) {
        out[b*6+0] = x0; out[b*6+1] = x1;
        out[b*6+2] = vx; out[b*6+3] = vp; out[b*6+4] = cxp;
        out[b*6+5] = state[b*6+5] + 2.048f;
        float* fo = out + 6*NBATCH + (size_t)NBATCH*NT*2;
        fo[b*2+0] = f0; fo[b*2+1] = f1;
    }
}

// Host: LFT step matrix for the Kalman form, raised to LSEG, in double.
static M16 build_m_pow(int log2l)
{
    const double dt = 0.001;
    const double a00 = -0.15, a01 = 6.283185, a10 = -6.283185, a11 = -0.15;
    const double qq = dt * 4.0 * 0.8 * 0.9;         // Cd = diag(qq,0)
    const double qd = dt * 5.25;                    // Qd = qd*I
    const double h00 = 1.0 + dt*a00, h01 = dt*a01;
    const double h10 = dt*a10,       h11 = 1.0 + dt*a11;
    const double det = h00*h11 - h01*h10;
    const double t00 = h11/det, t01 = -h10/det, t10 = -h01/det, t11 = h00/det;
    const double g00 = t00*qq, g10 = t10*qq;
    double M[4][4] = {
        { h00 + qd*g00, h01, qd*t00, qd*t01 },
        { h10 + qd*g10, h11, qd*t10, qd*t11 },
        { g00,          0.0, t00,    t01    },
        { g10,          0.0, t10,    t11    },
    };
    for (int it = 0; it < log2l; ++it) {
        double R[4][4];
        for (int i = 0; i < 4; ++i)
            for (int j = 0; j < 4; ++j) {
                double acc = 0.0;
                for (int k = 0; k < 4; ++k) acc += M[i][k]*M[k][j];
                R[i][j] = acc;
            }
        for (int i = 0; i < 4; ++i)
            for (int j = 0; j < 4; ++j) M[i][j] = R[i][j];
    }
    M16 r;
    for (int i = 0; i < 4; ++i)
        for (int j = 0; j < 4; ++j) r.m[i*4+j] = (float)M[i][j];
    return r;
}

template<int S>
static void launch_pair(const float* dy, const float* state, const float* fin,
                        const float* kp, float* ws, float* out, hipStream_t stream)
{
    M16 mc = build_m_pow(gk::cfg<S>::LOG2L);
    k1_xq<S><<<dim3(NBATCH/64, S), dim3(64), 0, stream>>>(dy, state, fin, kp, mc, ws);
    k2_replay<S><<<dim3(NBATCH/64, S), dim3(64), 0, stream>>>(dy, state, fin, kp, mc, ws, out);
}

extern "C" void kernel_launch(void* const* d_in, const int* in_sizes, int n_in,
                              void* d_out, int out_size, void* d_ws, size_t ws_size,
                              hipStream_t stream)
{
    const float* dy    = (const float*)d_in[0];
    const float* state = (const float*)d_in[1];
    const float* fin   = (const float*)d_in[2];
    const float* kp    = (const float*)d_in[3];
    float* out = (float*)d_out;
    float* ws  = (float*)d_ws;

    const size_t need = [](int S){ return (size_t)6 * S * NBATCH * sizeof(float); }
        (64);
    if (ws_size >= need)
        launch_pair<64>(dy, state, fin, kp, ws, out, stream);
    else if (ws_size >= (size_t)6 * 32 * NBATCH * sizeof(float))
        launch_pair<32>(dy, state, fin, kp, ws, out, stream);
    else
        launch_pair<16>(dy, state, fin, kp, ws, out, stream);
}

// Round 6
// 53.037 us; speedup vs baseline: 1.1061x; 1.1061x over previous
//
#include <hip/hip_runtime.h>
#include <cmath>

// GRNN_3547642986522 — B=4096 filters, T=2048 steps.
// k1: per (wave: 64 batches, segment s): O(1) LFT checkpoint (binary matpow of
//     the constant per-segment LFT matrix), accumulate per-segment 2x2 transfer
//     X / offset Q over LSEG steps (dy staged via LDS). Writes PQ [6][S][B].
// kfold: 4096 threads; per batch, fold the S segment maps sequentially with
//     8-segment register prefetch; overwrite planes 4/5 in place with
//     x-at-segment-start. Removes the O(S^2) per-block fold from k2.
// k2: per (wave, s): matpow checkpoint for cov/f, read x_start from planes 4/5,
//     replay LSEG steps emitting dy_hat (LDS-staged coalesced f4 stores).
//     s==S-1 writes nstate & fnew. 256-thread blocks (4 indep waves), no
//     __syncthreads, launch_bounds(256,4) -> 16 waves/CU.

#define NBATCH 4096
#define NT     2048
#define ROWF4  1024   // float4 per dy row
#define WPB    4      // waves per block

struct M16 { float m[16]; };

namespace gk {

constexpr float DT   = 0.001f;
constexpr float A00  = -0.15f;
constexpr float A01  = 6.283185f;
constexpr float A10  = -6.283185f;
constexpr float A11  = -0.15f;
constexpr float C0   = 1.6970562748477141f;
constexpr float DD   = 5.25f;

constexpr float P00c = 1.0f + DT*A00;
constexpr float P01c = DT*A01;
constexpr float P10c = DT*A10;
constexpr float P11c = 1.0f + DT*A11;
constexpr float DTC  = DT*C0;
constexpr float QQ   = DT*C0*C0;
constexpr float cVA  = 1.0f + 2.0f*DT*A00;
constexpr float cVB  = 2.0f*DT*A01;
constexpr float cVBn = 2.0f*DT*A10;
constexpr float cVD  = DT*DD;
constexpr float cCA  = 1.0f + DT*(A00+A11);
constexpr float cCB  = DT*A10;
constexpr float cCC  = DT*A01;
constexpr float YC   = C0*DT;

template<int S>
struct cfg {
    static constexpr int LSEG  = NT / S;
    static constexpr int NCHK  = LSEG / 32;
    static constexpr int LDSW  = 36;
    static constexpr int SEGF4 = LSEG / 2;
    static constexpr int PLANE = S * NBATCH;
    static constexpr int LOG2L = (LSEG == 32) ? 5 : (LSEG == 64) ? 6 : 7;
};

__device__ __forceinline__ void cov_step(float& vx, float& vp, float& cxp)
{
    float a1 = fmaf(-QQ, vx,  cVA);
    float b1 = fmaf(cVB, cxp, cVD);
    float a2 = fmaf(-QQ, cxp, cVBn);
    float b2 = fmaf(a2,  cxp, cVD);
    float a3 = fmaf(-QQ, vx,  cCA);
    float m  = cCC * vp;
    float c3 = fmaf(cCB, vx,  m);
    float nvx = fmaf(a1,  vx,  b1);
    float nvp = fmaf(cVA, vp,  b2);
    float ncx = fmaf(a3,  cxp, c3);
    vx = nvx; vp = nvp; cxp = ncx;
}

__device__ __forceinline__ void covf_step(
    float& vx, float& vp, float& cxp, float& f0, float& f1,
    float k00, float k01, float k10, float k11,
    float& xi0o, float& xi1o, float& nf0o)
{
    float xi0 = C0*vx, xi1 = C0*cxp;
    float nf0 = fmaf(DT, fmaf(k00, f0, k01*f1), f0);
    float nf1 = fmaf(DT, fmaf(k10, f0, k11*f1), f1);
    xi0o = xi0; xi1o = xi1; nf0o = nf0;
    cov_step(vx, vp, cxp);
    f0 = nf0; f1 = nf1;
}

__device__ __forceinline__ void mat4_mul(const float* A, const float* B, float* C)
{
    #pragma unroll
    for (int i = 0; i < 4; ++i)
        #pragma unroll
        for (int j = 0; j < 4; ++j) {
            float acc = A[i*4+0] * B[0*4+j];
            acc = fmaf(A[i*4+1], B[1*4+j], acc);
            acc = fmaf(A[i*4+2], B[2*4+j], acc);
            acc = fmaf(A[i*4+3], B[3*4+j], acc);
            C[i*4+j] = acc;
        }
}

__device__ __forceinline__ void lft_apply(const float* m, float& vx, float& vp, float& cxp)
{
    float n00 = fmaf(m[0], vx,  fmaf(m[1], cxp, m[2]));
    float n01 = fmaf(m[0], cxp, fmaf(m[1], vp,  m[3]));
    float n10 = fmaf(m[4], vx,  fmaf(m[5], cxp, m[6]));
    float n11 = fmaf(m[4], cxp, fmaf(m[5], vp,  m[7]));
    float d00 = fmaf(m[8],  vx,  fmaf(m[9],  cxp, m[10]));
    float d01 = fmaf(m[8],  cxp, fmaf(m[9],  vp,  m[11]));
    float d10 = fmaf(m[12], vx,  fmaf(m[13], cxp, m[14]));
    float d11 = fmaf(m[12], cxp, fmaf(m[13], vp,  m[15]));
    float rdet = 1.0f / fmaf(d00, d11, -d01*d10);
    float p00 = fmaf(n00, d11, -n01*d10) * rdet;
    float p01 = fmaf(n01, d00, -n00*d01) * rdet;
    float p10 = fmaf(n10, d11, -n11*d10) * rdet;
    float p11 = fmaf(n11, d00, -n10*d01) * rdet;
    vx = p00; vp = p11; cxp = 0.5f*(p01 + p10);
}

// cov via lft(ML^s), f via ((I+dtK)^LSEG)^s — binary matpow in registers.
template<int S>
__device__ __forceinline__ void seg_checkpoint(
    const M16& ml, int s, const float* state, const float* fin, int b,
    float k00, float k01, float k10, float k11,
    float& vx, float& vp, float& cxp, float& f0, float& f1)
{
    using namespace gk;
    vx = state[b*6+2]; vp = state[b*6+3]; cxp = state[b*6+4];
    f0 = fin[b*2+0];   f1 = fin[b*2+1];

    float acc[16] = {1,0,0,0, 0,1,0,0, 0,0,1,0, 0,0,0,1};
    float bas[16];
    #pragma unroll
    for (int i = 0; i < 16; ++i) bas[i] = ml.m[i];
    int e = s;
    #pragma unroll 1
    while (e) {
        float t[16];
        if (e & 1) {
            mat4_mul(acc, bas, t);
            #pragma unroll
            for (int i = 0; i < 16; ++i) acc[i] = t[i];
        }
        e >>= 1;
        if (e) {
            mat4_mul(bas, bas, t);
            #pragma unroll
            for (int i = 0; i < 16; ++i) bas[i] = t[i];
        }
    }
    lft_apply(acc, vx, vp, cxp);

    float m00 = fmaf(DT,k00,1.f), m01 = DT*k01;
    float m10 = DT*k10,           m11 = fmaf(DT,k11,1.f);
    #pragma unroll
    for (int i = 0; i < cfg<S>::LOG2L; ++i) {
        float a = fmaf(m00,m00, m01*m10);
        float q = fmaf(m00,m01, m01*m11);
        float c = fmaf(m10,m00, m11*m10);
        float d = fmaf(m10,m01, m11*m11);
        m00=a; m01=q; m10=c; m11=d;
    }
    float a00=1.f, a01=0.f, a10=0.f, a11=1.f;
    e = s;
    #pragma unroll 1
    while (e) {
        if (e & 1) {
            float x0 = fmaf(a00,m00, a01*m10);
            float x1 = fmaf(a00,m01, a01*m11);
            float x2 = fmaf(a10,m00, a11*m10);
            float x3 = fmaf(a10,m01, a11*m11);
            a00=x0; a01=x1; a10=x2; a11=x3;
        }
        e >>= 1;
        if (e) {
            float x0 = fmaf(m00,m00, m01*m10);
            float x1 = fmaf(m00,m01, m01*m11);
            float x2 = fmaf(m10,m00, m11*m10);
            float x3 = fmaf(m10,m01, m11*m11);
            m00=x0; m01=x1; m10=x2; m11=x3;
        }
    }
    float nf0 = fmaf(a00, f0, a01*f1);
    float nf1 = fmaf(a10, f0, a11*f1);
    f0 = nf0; f1 = nf1;
}

__device__ __forceinline__ float f4c(const float4& q, int c) {
    return c==0 ? q.x : c==1 ? q.y : c==2 ? q.z : q.w;
}
__device__ __forceinline__ void f4set(float4& q, int c, float v) {
    if (c==0) q.x=v; else if (c==1) q.y=v; else if (c==2) q.z=v; else q.w=v;
}

template<int S>
__device__ __forceinline__ void issue_loads(float4* stg, const float4* dy4,
                                            int b0, int s, int c, int lane)
{
    const int p = lane & 15, rl = lane >> 4;
    const float4* base = dy4 + (size_t)(b0 + rl) * ROWF4
                       + s*cfg<S>::SEGF4 + c*16 + p;
    #pragma unroll
    for (int i = 0; i < 16; ++i)
        stg[i] = base[(size_t)i * 4 * ROWF4];
}

} // namespace gk

// ---------------------------------------------------------------- k1
template<int S>
__global__ void __launch_bounds__(64*WPB, 4)
k1_xq(const float* __restrict__ dy, const float* __restrict__ state,
      const float* __restrict__ fin, const float* __restrict__ kp,
      M16 mc, float* __restrict__ ws)
{
    using namespace gk;
    constexpr int NCHK = cfg<S>::NCHK, LDSW = cfg<S>::LDSW, PLANE = cfg<S>::PLANE;
    __shared__ float lds[WPB][64][LDSW];
    const int lane = threadIdx.x & 63;
    const int wv   = threadIdx.x >> 6;
    const int b0   = (blockIdx.x*WPB + wv) * 64;
    const int s    = blockIdx.y;
    const int b    = b0 + lane;
    const int p    = lane & 15, rl = lane >> 4;
    const float k00 = kp[0], k01 = kp[1], k10 = kp[2], k11 = kp[3];

    const float4* dy4 = reinterpret_cast<const float4*>(dy);
    float4 stg[16];
    issue_loads<S>(stg, dy4, b0, s, 0, lane);   // in flight during checkpoint

    float vx, vp, cxp, f0, f1;
    seg_checkpoint<S>(mc, s, state, fin, b, k00, k01, k10, k11, vx, vp, cxp, f0, f1);

    float X00 = 1.f, X01 = 0.f, X10 = 0.f, X11 = 1.f, Q0 = 0.f, Q1 = 0.f;

    #pragma unroll 1
    for (int c = 0; c < NCHK; ++c) {
        #pragma unroll
        for (int i = 0; i < 16; ++i) {
            int row = 4*i + rl;
            *reinterpret_cast<float2*>(&lds[wv][row][2*p]) =
                make_float2(stg[i].x, stg[i].z);
        }
        if (c < NCHK-1) issue_loads<S>(stg, dy4, b0, s, c+1, lane);
        asm volatile("s_waitcnt lgkmcnt(0)" ::: "memory");
        __builtin_amdgcn_sched_barrier(0);

        float4 v[8];
        #pragma unroll
        for (int i = 0; i < 8; ++i)
            v[i] = *reinterpret_cast<const float4*>(&lds[wv][lane][4*i]);

        #pragma unroll
        for (int i = 0; i < 32; ++i) {
            float dy0 = f4c(v[i>>2], i & 3);
            float xi0, xi1, nf0;
            covf_step(vx, vp, cxp, f0, f1, k00, k01, k10, k11, xi0, xi1, nf0);
            float p00 = fmaf(-DTC, xi0, P00c);
            float p10 = fmaf(-DTC, xi1, P10c);
            float r0  = xi0*dy0;
            float r1  = fmaf(DT, nf0, xi1*dy0);
            float nX00 = fmaf(p00, X00, P01c*X10);
            float nX01 = fmaf(p00, X01, P01c*X11);
            float nX10 = fmaf(p10, X00, P11c*X10);
            float nX11 = fmaf(p10, X01, P11c*X11);
            float nQ0  = fmaf(p00, Q0, fmaf(P01c, Q1, r0));
            float nQ1  = fmaf(p10, Q0, fmaf(P11c, Q1, r1));
            X00 = nX00; X01 = nX01; X10 = nX10; X11 = nX11; Q0 = nQ0; Q1 = nQ1;
        }
    }

    float* PQ = ws;
    const int sb = s*NBATCH + b;
    PQ[0*PLANE+sb] = X00;  PQ[1*PLANE+sb] = X01;
    PQ[2*PLANE+sb] = X10;  PQ[3*PLANE+sb] = X11;
    PQ[4*PLANE+sb] = Q0;   PQ[5*PLANE+sb] = Q1;
}

// ---------------------------------------------------------------- kfold
// Fold segment maps per batch; overwrite planes 4/5 with x at segment start.
template<int S>
__global__ void __launch_bounds__(64, 1)
kfold(const float* __restrict__ state, float* __restrict__ ws)
{
    using namespace gk;
    constexpr int PLANE = cfg<S>::PLANE;
    constexpr int CH = 8, NC = S / CH;
    const int b = blockIdx.x*64 + threadIdx.x;

    float* p0 = ws + 0*PLANE; float* p1 = ws + 1*PLANE;
    float* p2 = ws + 2*PLANE; float* p3 = ws + 3*PLANE;
    float* p4 = ws + 4*PLANE; float* p5 = ws + 5*PLANE;

    float x0 = state[b*6+0], x1 = state[b*6+1];

    float cur[CH*6], nxt[CH*6];
    #pragma unroll
    for (int j = 0; j < CH; ++j) {
        int idx = j*NBATCH + b;
        cur[j*6+0]=p0[idx]; cur[j*6+1]=p1[idx]; cur[j*6+2]=p2[idx];
        cur[j*6+3]=p3[idx]; cur[j*6+4]=p4[idx]; cur[j*6+5]=p5[idx];
    }
    #pragma unroll 1
    for (int ch = 0; ch < NC; ++ch) {
        if (ch < NC-1) {
            #pragma unroll
            for (int j = 0; j < CH; ++j) {
                int idx = ((ch+1)*CH + j)*NBATCH + b;
                nxt[j*6+0]=p0[idx]; nxt[j*6+1]=p1[idx]; nxt[j*6+2]=p2[idx];
                nxt[j*6+3]=p3[idx]; nxt[j*6+4]=p4[idx]; nxt[j*6+5]=p5[idx];
            }
        }
        #pragma unroll
        for (int j = 0; j < CH; ++j) {
            int idx = (ch*CH + j)*NBATCH + b;
            p4[idx] = x0; p5[idx] = x1;            // x at segment start
            float nx0 = fmaf(cur[j*6+0], x0, fmaf(cur[j*6+1], x1, cur[j*6+4]));
            float nx1 = fmaf(cur[j*6+2], x0, fmaf(cur[j*6+3], x1, cur[j*6+5]));
            x0 = nx0; x1 = nx1;
        }
        #pragma unroll
        for (int i = 0; i < CH*6; ++i) cur[i] = nxt[i];
    }
}

// ---------------------------------------------------------------- k2
template<int S>
__global__ void __launch_bounds__(64*WPB, 4)
k2_replay(const float* __restrict__ dy, const float* __restrict__ state,
          const float* __restrict__ fin, const float* __restrict__ kp,
          M16 mc, const float* __restrict__ ws, float* __restrict__ out)
{
    using namespace gk;
    constexpr int NCHK = cfg<S>::NCHK, LDSW = cfg<S>::LDSW, PLANE = cfg<S>::PLANE;
    __shared__ float lds[WPB][64][LDSW];
    const int lane = threadIdx.x & 63;
    const int wv   = threadIdx.x >> 6;
    const int b0   = (blockIdx.x*WPB + wv) * 64;
    const int s    = blockIdx.y;
    const int b    = b0 + lane;
    const int p    = lane & 15, rl = lane >> 4;
    const float k00 = kp[0], k01 = kp[1], k10 = kp[2], k11 = kp[3];

    const float4* dy4 = reinterpret_cast<const float4*>(dy);
    float4 stg[16];
    issue_loads<S>(stg, dy4, b0, s, 0, lane);   // in flight during checkpoint

    float vx, vp, cxp, f0, f1;
    seg_checkpoint<S>(mc, s, state, fin, b, k00, k01, k10, k11, vx, vp, cxp, f0, f1);

    const int sb = s*NBATCH + b;
    float x0 = ws[4*PLANE + sb], x1 = ws[5*PLANE + sb];   // folded x_start

    float4* dh4 = reinterpret_cast<float4*>(out + 6*NBATCH);

    #pragma unroll 1
    for (int c = 0; c < NCHK; ++c) {
        #pragma unroll
        for (int i = 0; i < 16; ++i) {
            int row = 4*i + rl;
            *reinterpret_cast<float2*>(&lds[wv][row][2*p]) =
                make_float2(stg[i].x, stg[i].z);
        }
        if (c < NCHK-1) issue_loads<S>(stg, dy4, b0, s, c+1, lane);
        asm volatile("s_waitcnt lgkmcnt(0)" ::: "memory");
        __builtin_amdgcn_sched_barrier(0);

        float4 v[8];
        #pragma unroll
        for (int i = 0; i < 8; ++i)
            v[i] = *reinterpret_cast<const float4*>(&lds[wv][lane][4*i]);

        #pragma unroll
        for (int i = 0; i < 32; ++i) {
            float dy0 = f4c(v[i>>2], i & 3);
            float yh  = YC * x0;              // pre-update x
            f4set(v[i>>2], i & 3, yh);
            float xi0, xi1, nf0;
            covf_step(vx, vp, cxp, f0, f1, k00, k01, k10, k11, xi0, xi1, nf0);
            float p00 = fmaf(-DTC, xi0, P00c);
            float p10 = fmaf(-DTC, xi1, P10c);
            float r0  = xi0*dy0;
            float r1  = fmaf(DT, nf0, xi1*dy0);
            float nx0 = fmaf(p00, x0, fmaf(P01c, x1, r0));
            float nx1 = fmaf(p10, x0, fmaf(P11c, x1, r1));
            x0 = nx0; x1 = nx1;
        }
        #pragma unroll
        for (int i = 0; i < 8; ++i)
            *reinterpret_cast<float4*>(&lds[wv][lane][4*i]) = v[i];
        asm volatile("s_waitcnt lgkmcnt(0)" ::: "memory");
        __builtin_amdgcn_sched_barrier(0);

        #pragma unroll
        for (int i = 0; i < 16; ++i) {
            int row = 4*i + rl;
            float2 v2 = *reinterpret_cast<const float2*>(&lds[wv][row][2*p]);
            dh4[(size_t)(b0+row)*ROWF4 + s*cfg<S>::SEGF4 + c*16 + p] =
                make_float4(v2.x, 0.f, v2.y, 0.f);
        }
    }

    if (s == S-1) {
        out[b*6+0] = x0; out[b*6+1] = x1;
        out[b*6+2] = vx; out[b*6+3] = vp; out[b*6+4] = cxp;
        out[b*6+5] = state[b*6+5] + 2.048f;
        float* fo = out + 6*NBATCH + (size_t)NBATCH*NT*2;
        fo[b*2+0] = f0; fo[b*2+1] = f1;
    }
}

// Host: LFT step matrix (Kalman form) ^ LSEG, in double.
static M16 build_m_pow(int log2l)
{
    const double dt = 0.001;
    const double a00 = -0.15, a01 = 6.283185, a10 = -6.283185, a11 = -0.15;
    const double qq = dt * 4.0 * 0.8 * 0.9;
    const double qd = dt * 5.25;
    const double h00 = 1.0 + dt*a00, h01 = dt*a01;
    const double h10 = dt*a10,       h11 = 1.0 + dt*a11;
    const double det = h00*h11 - h01*h10;
    const double t00 = h11/det, t01 = -h10/det, t10 = -h01/det, t11 = h00/det;
    const double g00 = t00*qq, g10 = t10*qq;
    double M[4][4] = {
        { h00 + qd*g00, h01, qd*t00, qd*t01 },
        { h10 + qd*g10, h11, qd*t10, qd*t11 },
        { g00,          0.0, t00,    t01    },
        { g10,          0.0, t10,    t11    },
    };
    for (int it = 0; it < log2l; ++it) {
        double R[4][4];
        for (int i = 0; i < 4; ++i)
            for (int j = 0; j < 4; ++j) {
                double acc = 0.0;
                for (int k = 0; k < 4; ++k) acc += M[i][k]*M[k][j];
                R[i][j] = acc;
            }
        for (int i = 0; i < 4; ++i)
            for (int j = 0; j < 4; ++j) M[i][j] = R[i][j];
    }
    M16 r;
    for (int i = 0; i < 4; ++i)
        for (int j = 0; j < 4; ++j) r.m[i*4+j] = (float)M[i][j];
    return r;
}

template<int S>
static void launch_all(const float* dy, const float* state, const float* fin,
                       const float* kp, float* ws, float* out, hipStream_t stream)
{
    M16 mc = build_m_pow(gk::cfg<S>::LOG2L);
    dim3 blk(64*WPB);
    dim3 grid(NBATCH/(64*WPB), S);
    k1_xq<S><<<grid, blk, 0, stream>>>(dy, state, fin, kp, mc, ws);
    kfold<S><<<dim3(NBATCH/64), dim3(64), 0, stream>>>(state, ws);
    k2_replay<S><<<grid, blk, 0, stream>>>(dy, state, fin, kp, mc, ws, out);
}

extern "C" void kernel_launch(void* const* d_in, const int* in_sizes, int n_in,
                              void* d_out, int out_size, void* d_ws, size_t ws_size,
                              hipStream_t stream)
{
    const float* dy    = (const float*)d_in[0];
    const float* state = (const float*)d_in[1];
    const float* fin   = (const float*)d_in[2];
    const float* kp    = (const float*)d_in[3];
    float* out = (float*)d_out;
    float* ws  = (float*)d_ws;

    if (ws_size >= (size_t)6 * 64 * NBATCH * sizeof(float))
        launch_all<64>(dy, state, fin, kp, ws, out, stream);
    else if (ws_size >= (size_t)6 * 32 * NBATCH * sizeof(float))
        launch_all<32>(dy, state, fin, kp, ws, out, stream);
    else
        launch_all<16>(dy, state, fin, kp, ws, out, stream);
}